// Round 8
// baseline (119.252 us; speedup 1.0000x reference)
//
#include <hip/hip_runtime.h>
#include <hip/hip_bf16.h>

// Problem constants
#define BATCH 8
#define CDIM 256     // QDIM == KDIM
#define SEQ 1024     // 32*32
#define EMB 512
#define NHEAD 8
#define HDIM 64

typedef __bf16 bf16x8 __attribute__((ext_vector_type(8)));
typedef float f32x4 __attribute__((ext_vector_type(4)));
typedef float f32x16 __attribute__((ext_vector_type(16)));

static __device__ __forceinline__ unsigned short f2b(float f) {
    __hip_bfloat16 h = __float2bfloat16(f);
    return __builtin_bit_cast(unsigned short, h);
}

static __device__ __forceinline__ f32x4 mfma16(bf16x8 a, bf16x8 b, f32x4 c) {
    return __builtin_amdgcn_mfma_f32_16x16x32_bf16(a, b, c, 0, 0, 0);
}
static __device__ __forceinline__ f32x16 mfma32(bf16x8 a, bf16x8 b, f32x16 c) {
    return __builtin_amdgcn_mfma_f32_32x32x16_bf16(a, b, c, 0, 0, 0);
}

// async global->LDS, 16B per lane; LDS dest is wave-uniform base + lane*16
static __device__ __forceinline__ void gload16(const void* g, void* l) {
    __builtin_amdgcn_global_load_lds(
        (const __attribute__((address_space(1))) unsigned int*)g,
        (__attribute__((address_space(3))) unsigned int*)l, 16, 0, 0);
}

// Fragment-major intermediate layout (consumed by attn as coalesced
// base + lane*16B loads):
//   Qf/Kf slot: [bh][kt][dblk][lane]  lane = (s&31) + 32*((dd>>3)&1),
//               8 bf16 elems = dd&7, dblk = dd>>4.
//   Vf slot:    [bh][kt][sub][lane]   sub = (dd>>5)*2 + ((s>>4)&1),
//               lane = (dd&31) + 32*((s>>3)&1), elems = s&7.
// Each slot entry: 64 lanes * 16B = 512 shorts.

// ---------------------------------------------------------------------------
// Kernel 1: prep (unchanged from r7). z<16: transpose+convert X with T2
// XOR-swizzle in global layout; z>=16: W -> Wc bf16, same swizzle.
// grid (16, 4, 19), block 256
// ---------------------------------------------------------------------------
__global__ __launch_bounds__(256) void prep_kernel(
    const float* __restrict__ query, const float* __restrict__ key_,
    const float* __restrict__ Wq, const float* __restrict__ Wk,
    const float* __restrict__ Wv,
    unsigned short* __restrict__ Xq, unsigned short* __restrict__ Xk,
    unsigned short* __restrict__ Wc)
{
    int tid = threadIdx.x;
    int z = blockIdx.z;
    if (z >= 16) {  // W conversion path
        int pz = z - 16;
        const float* W = (pz == 0) ? Wq : (pz == 1 ? Wk : Wv);
        int lin = blockIdx.y * 16 + blockIdx.x;
        int idx = (lin * 256 + tid) * 8;
        int e7 = (idx >> 8) & 7;
        float4 v0 = *(const float4*)&W[idx];
        float4 v1 = *(const float4*)&W[idx + 4];
        int4 pk;
        pk.x = (int)((unsigned)f2b(v0.x) | ((unsigned)f2b(v0.y) << 16));
        pk.y = (int)((unsigned)f2b(v0.z) | ((unsigned)f2b(v0.w) << 16));
        pk.z = (int)((unsigned)f2b(v1.x) | ((unsigned)f2b(v1.y) << 16));
        pk.w = (int)((unsigned)f2b(v1.z) | ((unsigned)f2b(v1.w) << 16));
        int dsti = (idx & ~255) | ((idx & 255) ^ (e7 << 3));
        *(int4*)&Wc[(size_t)pz * (EMB * CDIM) + dsti] = pk;
        return;
    }
    __shared__ alignas(16) unsigned short sT[64 * 66];
    int s0 = blockIdx.x * 64, c0 = blockIdx.y * 64;
    int which = z >> 3, b = z & 7;
    const float* src = which ? key_ : query;
    unsigned short* dst = which ? Xk : Xq;

#pragma unroll
    for (int p = 0; p < 4; ++p) {
        int c = (tid >> 4) + p * 16;
        int sch = tid & 15;
        float4 v = *(const float4*)&src[((size_t)b * CDIM + c0 + c) * SEQ + s0 + sch * 4];
        sT[c * 66 + sch * 4 + 0] = f2b(v.x);
        sT[c * 66 + sch * 4 + 1] = f2b(v.y);
        sT[c * 66 + sch * 4 + 2] = f2b(v.z);
        sT[c * 66 + sch * 4 + 3] = f2b(v.w);
    }
    __syncthreads();
#pragma unroll
    for (int p = 0; p < 4; ++p) {
        int s = (tid >> 4) + p * 16;
        int cch = tid & 15;
        unsigned short e0 = sT[(cch * 4 + 0) * 66 + s];
        unsigned short e1 = sT[(cch * 4 + 1) * 66 + s];
        unsigned short e2 = sT[(cch * 4 + 2) * 66 + s];
        unsigned short e3 = sT[(cch * 4 + 3) * 66 + s];
        uint2 pk;
        pk.x = (unsigned)e0 | ((unsigned)e1 << 16);
        pk.y = (unsigned)e2 | ((unsigned)e3 << 16);
        int col = (cch * 4) ^ ((s & 7) << 3);
        *(uint2*)&dst[((size_t)b * SEQ + s0 + s) * CDIM + c0 + col] = pk;
    }
}

// ---------------------------------------------------------------------------
// Kernel 2: fused projection GEMM. NEW (T3 minimum 2-phase): double-buffered
// LDS; per K-step a SINGLE __syncthreads (drains vmcnt -> current buffer
// ready), then issue next tile's global_load_lds immediately so its latency
// hides under this tile's MFMAs. Was: 2 barriers/step, fully serial staging.
// Bias loads hoisted above the K-loop. Epilogue: fragment-major stores (r7).
// grid (12, 64), block 256
// ---------------------------------------------------------------------------
__global__ __launch_bounds__(256) void proj_kernel(
    const unsigned short* __restrict__ Xq, const unsigned short* __restrict__ Xk,
    const unsigned short* __restrict__ Wc,
    const float* __restrict__ bq, const float* __restrict__ bk,
    const float* __restrict__ bv,
    unsigned short* __restrict__ Qf, unsigned short* __restrict__ Kf,
    unsigned short* __restrict__ Vf)
{
    __shared__ alignas(16) unsigned short sX[2][128 * 64];
    __shared__ alignas(16) unsigned short sW[2][128 * 64];
    int tid = threadIdx.x;
    int n0 = blockIdx.x * 128;
    int m0 = blockIdx.y * 128;
    int proj = n0 >> 9;
    const unsigned short* X = (proj == 0) ? Xq : Xk;
    const float* bias = (proj == 0) ? bq : (proj == 1 ? bk : bv);

    int lane = tid & 63, w = tid >> 6;
    int l16 = lane & 15, lhi = lane >> 4;
    int wr = w >> 1, wc = w & 1;
    int lrow = lane >> 3, lcb = (lane & 7) * 8;

    // hoist bias loads above the pipeline (keeps epilogue vmem out of it)
    float4 bi4[4];
    float bj[4];
    if (proj != 2) {
#pragma unroll
        for (int i = 0; i < 4; ++i)
            bi4[i] = *(const float4*)&bias[(n0 & 511) + wr * 64 + i * 16 + lhi * 4];
    } else {
#pragma unroll
        for (int j = 0; j < 4; ++j)
            bj[j] = bias[(n0 & 511) + wc * 64 + j * 16 + l16];
    }

    f32x4 zero = {0.f, 0.f, 0.f, 0.f};
    f32x4 acc[4][4];
#pragma unroll
    for (int i = 0; i < 4; ++i)
#pragma unroll
        for (int j = 0; j < 4; ++j) acc[i][j] = zero;

    auto stage = [&](int buf, int kt) {
        int c0 = kt * 64;
#pragma unroll
        for (int i = 0; i < 4; ++i) {
            int seg = i * 4 + w;            // 16 segments of 8 rows
            int row = seg * 8 + lrow;
            gload16(&X[(size_t)(m0 + row) * CDIM + c0 + lcb], &sX[buf][seg * 512]);
            gload16(&Wc[(size_t)(n0 + row) * CDIM + c0 + lcb], &sW[buf][seg * 512]);
        }
    };

    stage(0, 0);
    for (int kt = 0; kt < 4; ++kt) {
        int cur = kt & 1;
        __syncthreads();                 // vmcnt(0): buffer `cur` fully landed;
                                         // also fences last iter's LDS reads
        if (kt < 3) stage(cur ^ 1, kt + 1);  // next tile flies under this MFMA
        const unsigned short* tA = (proj == 2) ? &sX[cur][0] : &sW[cur][0];
        const unsigned short* tB = (proj == 2) ? &sW[cur][0] : &sX[cur][0];
#pragma unroll
        for (int kk = 0; kk < 2; ++kk) {
            bf16x8 af[4], bfr[4];
#pragma unroll
            for (int i = 0; i < 4; ++i) {
                int r = wr * 64 + i * 16 + l16;
                af[i] = *(const bf16x8*)&tA[r * 64 + ((kk * 32 + lhi * 8) ^ ((r & 7) << 3))];
            }
#pragma unroll
            for (int j = 0; j < 4; ++j) {
                int r = wc * 64 + j * 16 + l16;
                bfr[j] = *(const bf16x8*)&tB[r * 64 + ((kk * 32 + lhi * 8) ^ ((r & 7) << 3))];
            }
#pragma unroll
            for (int i = 0; i < 4; ++i)
#pragma unroll
                for (int j = 0; j < 4; ++j)
                    acc[i][j] = mfma16(af[i], bfr[j], acc[i][j]);
        }
    }

    if (proj != 2) {
        // swapped: e = (n0&511)+wr*64+i*16+lhi*4+r ; s = m0+wc*64+j*16+l16
        unsigned short* dst = proj ? Kf : Qf;
        float scale = proj ? 1.0f : (0.125f * 1.44269504f);  // Q: /sqrt(64)*log2e
#pragma unroll
        for (int i = 0; i < 4; ++i) {
            int e0 = (n0 & 511) + wr * 64 + i * 16 + lhi * 4;
            float4 bv4 = bi4[i];
            int hh = e0 >> 6, dd = e0 & 63;
            int dblk = dd >> 4, hib = (dd >> 3) & 1, jb = dd & 7;  // jb in {0,4}
#pragma unroll
            for (int j = 0; j < 4; ++j) {
                int mg = m0 + wc * 64 + j * 16 + l16;
                int bb = mg >> 10, s = mg & 1023;
                int bh = bb * NHEAD + hh;
                size_t idx = ((size_t)((bh * 32 + (s >> 5)) * 4 + dblk)) * 512 +
                             ((s & 31) + 32 * hib) * 8 + jb;
                uint2 pk;
                pk.x = (unsigned)f2b((acc[i][j][0] + bv4.x) * scale) |
                       ((unsigned)f2b((acc[i][j][1] + bv4.y) * scale) << 16);
                pk.y = (unsigned)f2b((acc[i][j][2] + bv4.z) * scale) |
                       ((unsigned)f2b((acc[i][j][3] + bv4.w) * scale) << 16);
                *(uint2*)&dst[idx] = pk;
            }
        }
    } else {
        // unswapped: s = m0+wr*64+i*16+lhi*4+r ; e = (n0&511)+wc*64+j*16+l16
#pragma unroll
        for (int j = 0; j < 4; ++j) {
            int e = (n0 & 511) + wc * 64 + j * 16 + l16;
            float bval = bj[j];
            int hh = e >> 6, dd = e & 63;
            int t2 = dd >> 5, lr = dd & 31;
#pragma unroll
            for (int i = 0; i < 4; ++i) {
                int mg = m0 + wr * 64 + i * 16 + lhi * 4;
                int bb = mg >> 10, s = mg & 1023;   // s..s+3, s&3==0
                int bh = bb * NHEAD + hh;
                int sub = t2 * 2 + ((s >> 4) & 1);
                size_t idx = ((size_t)((bh * 32 + (s >> 5)) * 4 + sub)) * 512 +
                             (lr + 32 * ((s >> 3) & 1)) * 8 + (s & 7);
                uint2 pk;
                pk.x = (unsigned)f2b(acc[i][j][0] + bval) |
                       ((unsigned)f2b(acc[i][j][1] + bval) << 16);
                pk.y = (unsigned)f2b(acc[i][j][2] + bval) |
                       ((unsigned)f2b(acc[i][j][3] + bval) << 16);
                *(uint2*)&Vf[idx] = pk;
            }
        }
    }
}

// ---------------------------------------------------------------------------
// Kernel 3: causal flash attention (unchanged from r7 — fragment-major
// coalesced loads, KVBLK=64, in-register softmax, setprio, no LDS/barriers).
// grid (B*H=64, 32), 64 threads.
// ---------------------------------------------------------------------------
__global__ __launch_bounds__(64, 3) void attn_kernel(
    const unsigned short* __restrict__ Qf, const unsigned short* __restrict__ Kf,
    const unsigned short* __restrict__ Vf, float* __restrict__ out)
{
    int lane = threadIdx.x;
    int l32 = lane & 31, hi = lane >> 5;
    int bh = blockIdx.x;
    int qt = (int)(gridDim.y - 1 - blockIdx.y);
    int b = bh >> 3, h = bh & 7;
    int q0 = qt * 32;

    const unsigned short* Qs = Qf + ((size_t)(bh * 32 + qt)) * 2048;
    const unsigned short* Khd = Kf + (size_t)bh * 32 * 2048;
    const unsigned short* Vhd = Vf + (size_t)bh * 32 * 2048;

    bf16x8 qf[4];
#pragma unroll
    for (int d = 0; d < 4; ++d)
        qf[d] = *(const bf16x8*)&Qs[d * 512 + lane * 8];

    f32x16 o0, o1;
#pragma unroll
    for (int r = 0; r < 16; ++r) { o0[r] = 0.f; o1[r] = 0.f; }
    float m = -1e30f, l = 0.f;

    bf16x8 kA[8], vv[8];

    auto loadK64 = [&](int kt) {
#pragma unroll
        for (int h2 = 0; h2 < 2; ++h2)
#pragma unroll
            for (int d = 0; d < 4; ++d)
                kA[h2 * 4 + d] = *(const bf16x8*)
                    &Khd[(size_t)(kt + h2) * 2048 + d * 512 + lane * 8];
    };
    auto loadK32 = [&](int kt) {
#pragma unroll
        for (int d = 0; d < 4; ++d)
            kA[d] = *(const bf16x8*)&Khd[(size_t)kt * 2048 + d * 512 + lane * 8];
    };
    auto loadV64 = [&](int kt) {
#pragma unroll
        for (int t2 = 0; t2 < 2; ++t2)
#pragma unroll
            for (int kk = 0; kk < 2; ++kk) {
                vv[t2 * 4 + kk] = *(const bf16x8*)
                    &Vhd[(size_t)kt * 2048 + (t2 * 2 + kk) * 512 + lane * 8];
                vv[t2 * 4 + 2 + kk] = *(const bf16x8*)
                    &Vhd[(size_t)(kt + 1) * 2048 + (t2 * 2 + kk) * 512 + lane * 8];
            }
    };
    auto loadV32 = [&](int kt) {
#pragma unroll
        for (int t2 = 0; t2 < 2; ++t2)
#pragma unroll
            for (int kk = 0; kk < 2; ++kk)
                vv[t2 * 4 + kk] = *(const bf16x8*)
                    &Vhd[(size_t)kt * 2048 + (t2 * 2 + kk) * 512 + lane * 8];
    };
    auto packP = [&](const f32x16& st, bf16x8& pbA, bf16x8& pbB) {
        unsigned u[8];
#pragma unroll
        for (int i = 0; i < 8; ++i) {
            unsigned r_;
            asm("v_cvt_pk_bf16_f32 %0, %1, %2" : "=v"(r_) : "v"(st[2 * i]), "v"(st[2 * i + 1]));
            u[i] = r_;
        }
        asm("v_permlane32_swap_b32 %0, %1" : "+v"(u[0]), "+v"(u[2]));
        asm("v_permlane32_swap_b32 %0, %1" : "+v"(u[1]), "+v"(u[3]));
        asm("v_permlane32_swap_b32 %0, %1" : "+v"(u[4]), "+v"(u[6]));
        asm("v_permlane32_swap_b32 %0, %1" : "+v"(u[5]), "+v"(u[7]));
        uint4 w0 = {u[0], u[1], u[2], u[3]};
        uint4 w1 = {u[4], u[5], u[6], u[7]};
        pbA = __builtin_bit_cast(bf16x8, w0);
        pbB = __builtin_bit_cast(bf16x8, w1);
    };

    auto tile64 = [&](bool maskDiag) {
        f32x16 st0, st1;
#pragma unroll
        for (int r = 0; r < 16; ++r) { st0[r] = 0.f; st1[r] = 0.f; }
        __builtin_amdgcn_s_setprio(1);
#pragma unroll
        for (int d = 0; d < 4; ++d) st0 = mfma32(kA[d], qf[d], st0);
#pragma unroll
        for (int d = 0; d < 4; ++d) st1 = mfma32(kA[4 + d], qf[d], st1);
        __builtin_amdgcn_s_setprio(0);
        if (maskDiag) {  // second half-tile is the diagonal
#pragma unroll
            for (int r = 0; r < 16; ++r) {
                int cd = (r & 3) + 8 * (r >> 2) + 4 * hi;
                if (cd > l32) st1[r] = -1e38f;
            }
        }
        float t16[16];
#pragma unroll
        for (int r = 0; r < 16; ++r) t16[r] = fmaxf(st0[r], st1[r]);
        float t8[8];
#pragma unroll
        for (int r = 0; r < 8; ++r) t8[r] = fmaxf(t16[r], t16[r + 8]);
        float t4[4];
#pragma unroll
        for (int r = 0; r < 4; ++r) t4[r] = fmaxf(t8[r], t8[r + 4]);
        float tmax = fmaxf(fmaxf(t4[0], t4[2]), fmaxf(t4[1], t4[3]));
        tmax = fmaxf(tmax, __shfl_xor(tmax, 32));
        if (!__all(tmax <= m + 8.0f)) {  // defer-max, exp2 domain
            float mnew = fmaxf(m, tmax);
            float corr = __builtin_amdgcn_exp2f(m - mnew);
#pragma unroll
            for (int r = 0; r < 16; ++r) { o0[r] *= corr; o1[r] *= corr; }
            l *= corr;
            m = mnew;
        }
#pragma unroll
        for (int r = 0; r < 16; ++r) {
            st0[r] = __builtin_amdgcn_exp2f(st0[r] - m);
            st1[r] = __builtin_amdgcn_exp2f(st1[r] - m);
        }
        float s16[16];
#pragma unroll
        for (int r = 0; r < 16; ++r) s16[r] = st0[r] + st1[r];
        float s8[8];
#pragma unroll
        for (int r = 0; r < 8; ++r) s8[r] = s16[r] + s16[r + 8];
        float s4[4];
#pragma unroll
        for (int r = 0; r < 4; ++r) s4[r] = s8[r] + s8[r + 4];
        float ts = (s4[0] + s4[2]) + (s4[1] + s4[3]);
        ts += __shfl_xor(ts, 32);
        l += ts;
        bf16x8 pb0, pb1, pb2, pb3;
        packP(st0, pb0, pb1);
        packP(st1, pb2, pb3);
        __builtin_amdgcn_s_setprio(1);
        o0 = mfma32(vv[0], pb0, o0); o1 = mfma32(vv[4], pb0, o1);
        o0 = mfma32(vv[1], pb1, o0); o1 = mfma32(vv[5], pb1, o1);
        o0 = mfma32(vv[2], pb2, o0); o1 = mfma32(vv[6], pb2, o1);
        o0 = mfma32(vv[3], pb3, o0); o1 = mfma32(vv[7], pb3, o1);
        __builtin_amdgcn_s_setprio(0);
    };

    auto tile32 = [&](bool mask) {  // diagonal 32-wide tile at q0
        f32x16 st0;
#pragma unroll
        for (int r = 0; r < 16; ++r) st0[r] = 0.f;
        __builtin_amdgcn_s_setprio(1);
#pragma unroll
        for (int d = 0; d < 4; ++d) st0 = mfma32(kA[d], qf[d], st0);
        __builtin_amdgcn_s_setprio(0);
        if (mask) {
#pragma unroll
            for (int r = 0; r < 16; ++r) {
                int cd = (r & 3) + 8 * (r >> 2) + 4 * hi;
                if (cd > l32) st0[r] = -1e38f;
            }
        }
        float t8[8];
#pragma unroll
        for (int r = 0; r < 8; ++r) t8[r] = fmaxf(st0[r], st0[r + 8]);
        float t4[4];
#pragma unroll
        for (int r = 0; r < 4; ++r) t4[r] = fmaxf(t8[r], t8[r + 4]);
        float tmax = fmaxf(fmaxf(t4[0], t4[2]), fmaxf(t4[1], t4[3]));
        tmax = fmaxf(tmax, __shfl_xor(tmax, 32));
        if (!__all(tmax <= m + 8.0f)) {
            float mnew = fmaxf(m, tmax);
            float corr = __builtin_amdgcn_exp2f(m - mnew);
#pragma unroll
            for (int r = 0; r < 16; ++r) { o0[r] *= corr; o1[r] *= corr; }
            l *= corr;
            m = mnew;
        }
#pragma unroll
        for (int r = 0; r < 16; ++r) st0[r] = __builtin_amdgcn_exp2f(st0[r] - m);
        float s8[8];
#pragma unroll
        for (int r = 0; r < 8; ++r) s8[r] = st0[r] + st0[r + 8];
        float s4[4];
#pragma unroll
        for (int r = 0; r < 4; ++r) s4[r] = s8[r] + s8[r + 4];
        float ts = (s4[0] + s4[2]) + (s4[1] + s4[3]);
        ts += __shfl_xor(ts, 32);
        l += ts;
        bf16x8 pb0, pb1;
        packP(st0, pb0, pb1);
        __builtin_amdgcn_s_setprio(1);
        o0 = mfma32(vv[0], pb0, o0); o0 = mfma32(vv[1], pb1, o0);
        o1 = mfma32(vv[4], pb0, o1); o1 = mfma32(vv[5], pb1, o1);
        __builtin_amdgcn_s_setprio(0);
    };

    int nt64 = (qt + 1) >> 1;
    bool tail = ((qt & 1) == 0);  // qt even: diagonal handled by tile32
    for (int t = 0; t < nt64; ++t) {
        loadK64(2 * t);
        loadV64(2 * t);
        tile64((t == nt64 - 1) && !tail);
    }
    if (tail) {
        loadK32(qt);
        loadV32(qt);
        tile32(true);
    }

    float inv = 1.0f / l;
    size_t base = ((size_t)b * EMB + h * HDIM) * SEQ + q0 + l32;
#pragma unroll
    for (int r = 0; r < 16; ++r) {
        int d0 = (r & 3) + 8 * (r >> 2) + 4 * hi;
        out[base + (size_t)d0 * SEQ] = o0[r] * inv;
        out[base + (size_t)(d0 + 32) * SEQ] = o1[r] * inv;
    }
}

// ---------------------------------------------------------------------------
extern "C" void kernel_launch(void* const* d_in, const int* in_sizes, int n_in,
                              void* d_out, int out_size, void* d_ws, size_t ws_size,
                              hipStream_t stream) {
    const float* query = (const float*)d_in[0];
    const float* key_  = (const float*)d_in[1];
    const float* Wq    = (const float*)d_in[2];
    const float* bq    = (const float*)d_in[3];
    const float* Wk    = (const float*)d_in[4];
    const float* bk    = (const float*)d_in[5];
    const float* Wv    = (const float*)d_in[6];
    const float* bv    = (const float*)d_in[7];
    float* out = (float*)d_out;

    char* ws = (char*)d_ws;
    unsigned short* Qf = (unsigned short*)(ws);                    // 8 MiB frag-major
    unsigned short* Kf = (unsigned short*)(ws + 8388608);          // 8 MiB frag-major
    unsigned short* Vf = (unsigned short*)(ws + 16777216);         // 8 MiB frag-major
    unsigned short* Xq = (unsigned short*)(ws + 25165824);         // 4 MiB (B,S,C) swz
    unsigned short* Xk = (unsigned short*)(ws + 29360128);         // 4 MiB (B,S,C) swz
    // Wc (1536x256 bf16 swizzled, 768 KiB) in the tail of d_out; attn
    // overwrites all of d_out afterwards (stream-ordered) -> free scratch.
    unsigned short* Wc = (unsigned short*)((char*)d_out + 16777216 - 1048576);

    prep_kernel<<<dim3(16, 4, 19), 256, 0, stream>>>(query, key_, Wq, Wk, Wv, Xq, Xk, Wc);
    proj_kernel<<<dim3(12, 64), 256, 0, stream>>>(Xq, Xk, Wc, bq, bk, bv, Qf, Kf, Vf);
    attn_kernel<<<dim3(BATCH * NHEAD, SEQ / 32), 64, 0, stream>>>(Qf, Kf, Vf, out);
}

// Round 9
// 116.089 us; speedup vs baseline: 1.0272x; 1.0272x over previous
//
#include <hip/hip_runtime.h>
#include <hip/hip_bf16.h>

// Problem constants
#define BATCH 8
#define CDIM 256     // QDIM == KDIM
#define SEQ 1024     // 32*32
#define EMB 512
#define NHEAD 8
#define HDIM 64

typedef __bf16 bf16x8 __attribute__((ext_vector_type(8)));
typedef float f32x4 __attribute__((ext_vector_type(4)));
typedef float f32x16 __attribute__((ext_vector_type(16)));

static __device__ __forceinline__ unsigned short f2b(float f) {
    __hip_bfloat16 h = __float2bfloat16(f);
    return __builtin_bit_cast(unsigned short, h);
}

static __device__ __forceinline__ f32x4 mfma16(bf16x8 a, bf16x8 b, f32x4 c) {
    return __builtin_amdgcn_mfma_f32_16x16x32_bf16(a, b, c, 0, 0, 0);
}
static __device__ __forceinline__ f32x16 mfma32(bf16x8 a, bf16x8 b, f32x16 c) {
    return __builtin_amdgcn_mfma_f32_32x32x16_bf16(a, b, c, 0, 0, 0);
}

// async global->LDS, 16B per lane; LDS dest is wave-uniform base + lane*16
static __device__ __forceinline__ void gload16(const void* g, void* l) {
    __builtin_amdgcn_global_load_lds(
        (const __attribute__((address_space(1))) unsigned int*)g,
        (__attribute__((address_space(3))) unsigned int*)l, 16, 0, 0);
}

// Fragment-major intermediate layout (consumed by attn as coalesced
// base + lane*16B loads):
//   Qf/Kf slot: [bh][kt][dblk][lane]  lane = (s&31) + 32*((dd>>3)&1),
//               8 bf16 elems = dd&7, dblk = dd>>4.
//   Vf slot:    [bh][kt][sub][lane]   sub = (dd>>5)*2 + ((s>>4)&1),
//               lane = (dd&31) + 32*((s>>3)&1), elems = s&7.
// Each slot entry: 64 lanes * 16B = 512 shorts.

// ---------------------------------------------------------------------------
// Kernel 1: prep (unchanged). z<16: transpose+convert X with T2 XOR-swizzle
// in global layout; z>=16: W -> Wc bf16, same swizzle.
// grid (16, 4, 19), block 256
// ---------------------------------------------------------------------------
__global__ __launch_bounds__(256) void prep_kernel(
    const float* __restrict__ query, const float* __restrict__ key_,
    const float* __restrict__ Wq, const float* __restrict__ Wk,
    const float* __restrict__ Wv,
    unsigned short* __restrict__ Xq, unsigned short* __restrict__ Xk,
    unsigned short* __restrict__ Wc)
{
    int tid = threadIdx.x;
    int z = blockIdx.z;
    if (z >= 16) {  // W conversion path
        int pz = z - 16;
        const float* W = (pz == 0) ? Wq : (pz == 1 ? Wk : Wv);
        int lin = blockIdx.y * 16 + blockIdx.x;
        int idx = (lin * 256 + tid) * 8;
        int e7 = (idx >> 8) & 7;
        float4 v0 = *(const float4*)&W[idx];
        float4 v1 = *(const float4*)&W[idx + 4];
        int4 pk;
        pk.x = (int)((unsigned)f2b(v0.x) | ((unsigned)f2b(v0.y) << 16));
        pk.y = (int)((unsigned)f2b(v0.z) | ((unsigned)f2b(v0.w) << 16));
        pk.z = (int)((unsigned)f2b(v1.x) | ((unsigned)f2b(v1.y) << 16));
        pk.w = (int)((unsigned)f2b(v1.z) | ((unsigned)f2b(v1.w) << 16));
        int dsti = (idx & ~255) | ((idx & 255) ^ (e7 << 3));
        *(int4*)&Wc[(size_t)pz * (EMB * CDIM) + dsti] = pk;
        return;
    }
    __shared__ alignas(16) unsigned short sT[64 * 66];
    int s0 = blockIdx.x * 64, c0 = blockIdx.y * 64;
    int which = z >> 3, b = z & 7;
    const float* src = which ? key_ : query;
    unsigned short* dst = which ? Xk : Xq;

#pragma unroll
    for (int p = 0; p < 4; ++p) {
        int c = (tid >> 4) + p * 16;
        int sch = tid & 15;
        float4 v = *(const float4*)&src[((size_t)b * CDIM + c0 + c) * SEQ + s0 + sch * 4];
        sT[c * 66 + sch * 4 + 0] = f2b(v.x);
        sT[c * 66 + sch * 4 + 1] = f2b(v.y);
        sT[c * 66 + sch * 4 + 2] = f2b(v.z);
        sT[c * 66 + sch * 4 + 3] = f2b(v.w);
    }
    __syncthreads();
#pragma unroll
    for (int p = 0; p < 4; ++p) {
        int s = (tid >> 4) + p * 16;
        int cch = tid & 15;
        unsigned short e0 = sT[(cch * 4 + 0) * 66 + s];
        unsigned short e1 = sT[(cch * 4 + 1) * 66 + s];
        unsigned short e2 = sT[(cch * 4 + 2) * 66 + s];
        unsigned short e3 = sT[(cch * 4 + 3) * 66 + s];
        uint2 pk;
        pk.x = (unsigned)e0 | ((unsigned)e1 << 16);
        pk.y = (unsigned)e2 | ((unsigned)e3 << 16);
        int col = (cch * 4) ^ ((s & 7) << 3);
        *(uint2*)&dst[((size_t)b * SEQ + s0 + s) * CDIM + c0 + col] = pk;
    }
}

// ---------------------------------------------------------------------------
// Kernel 2: fused projection GEMM (r7 single-buffer version — r8's 64KB
// double-buffer was neutral: pipeline gain == occupancy loss; reverted).
// Staging: global_load_lds into unpadded [128][64] LDS, pre-swizzled inputs.
// Epilogue: fragment-major stores. grid (12, 64), block 256
// ---------------------------------------------------------------------------
__global__ __launch_bounds__(256) void proj_kernel(
    const unsigned short* __restrict__ Xq, const unsigned short* __restrict__ Xk,
    const unsigned short* __restrict__ Wc,
    const float* __restrict__ bq, const float* __restrict__ bk,
    const float* __restrict__ bv,
    unsigned short* __restrict__ Qf, unsigned short* __restrict__ Kf,
    unsigned short* __restrict__ Vf)
{
    __shared__ alignas(16) unsigned short sX[128 * 64];
    __shared__ alignas(16) unsigned short sW[128 * 64];
    int tid = threadIdx.x;
    int n0 = blockIdx.x * 128;
    int m0 = blockIdx.y * 128;
    int proj = n0 >> 9;
    const unsigned short* X = (proj == 0) ? Xq : Xk;
    const float* bias = (proj == 0) ? bq : (proj == 1 ? bk : bv);

    int lane = tid & 63, w = tid >> 6;
    int l16 = lane & 15, lhi = lane >> 4;
    int wr = w >> 1, wc = w & 1;
    int lrow = lane >> 3, lcb = (lane & 7) * 8;

    f32x4 zero = {0.f, 0.f, 0.f, 0.f};
    f32x4 acc[4][4];
#pragma unroll
    for (int i = 0; i < 4; ++i)
#pragma unroll
        for (int j = 0; j < 4; ++j) acc[i][j] = zero;

    for (int kt = 0; kt < 4; ++kt) {
        int c0 = kt * 64;
        if (kt) __syncthreads();
#pragma unroll
        for (int i = 0; i < 4; ++i) {
            int seg = i * 4 + w;
            int row = seg * 8 + lrow;
            gload16(&X[(size_t)(m0 + row) * CDIM + c0 + lcb], &sX[seg * 512]);
            gload16(&Wc[(size_t)(n0 + row) * CDIM + c0 + lcb], &sW[seg * 512]);
        }
        __syncthreads();
        const unsigned short* tA = (proj == 2) ? &sX[0] : &sW[0];
        const unsigned short* tB = (proj == 2) ? &sW[0] : &sX[0];
#pragma unroll
        for (int kk = 0; kk < 2; ++kk) {
            bf16x8 af[4], bfr[4];
#pragma unroll
            for (int i = 0; i < 4; ++i) {
                int r = wr * 64 + i * 16 + l16;
                af[i] = *(const bf16x8*)&tA[r * 64 + ((kk * 32 + lhi * 8) ^ ((r & 7) << 3))];
            }
#pragma unroll
            for (int j = 0; j < 4; ++j) {
                int r = wc * 64 + j * 16 + l16;
                bfr[j] = *(const bf16x8*)&tB[r * 64 + ((kk * 32 + lhi * 8) ^ ((r & 7) << 3))];
            }
#pragma unroll
            for (int i = 0; i < 4; ++i)
#pragma unroll
                for (int j = 0; j < 4; ++j)
                    acc[i][j] = mfma16(af[i], bfr[j], acc[i][j]);
        }
    }

    if (proj != 2) {
        // swapped: e = (n0&511)+wr*64+i*16+lhi*4+r ; s = m0+wc*64+j*16+l16
        unsigned short* dst = proj ? Kf : Qf;
        float scale = proj ? 1.0f : (0.125f * 1.44269504f);  // Q: /sqrt(64)*log2e
#pragma unroll
        for (int i = 0; i < 4; ++i) {
            int e0 = (n0 & 511) + wr * 64 + i * 16 + lhi * 4;
            float4 bv4 = *(const float4*)&bias[e0];
            int hh = e0 >> 6, dd = e0 & 63;
            int dblk = dd >> 4, hib = (dd >> 3) & 1, jb = dd & 7;  // jb in {0,4}
#pragma unroll
            for (int j = 0; j < 4; ++j) {
                int mg = m0 + wc * 64 + j * 16 + l16;
                int bb = mg >> 10, s = mg & 1023;
                int bh = bb * NHEAD + hh;
                size_t idx = ((size_t)((bh * 32 + (s >> 5)) * 4 + dblk)) * 512 +
                             ((s & 31) + 32 * hib) * 8 + jb;
                uint2 pk;
                pk.x = (unsigned)f2b((acc[i][j][0] + bv4.x) * scale) |
                       ((unsigned)f2b((acc[i][j][1] + bv4.y) * scale) << 16);
                pk.y = (unsigned)f2b((acc[i][j][2] + bv4.z) * scale) |
                       ((unsigned)f2b((acc[i][j][3] + bv4.w) * scale) << 16);
                *(uint2*)&dst[idx] = pk;
            }
        }
    } else {
        // unswapped: s = m0+wr*64+i*16+lhi*4+r ; e = (n0&511)+wc*64+j*16+l16
#pragma unroll
        for (int j = 0; j < 4; ++j) {
            int e = (n0 & 511) + wc * 64 + j * 16 + l16;
            float bval = bias[e];
            int hh = e >> 6, dd = e & 63;
            int t2 = dd >> 5, lr = dd & 31;
#pragma unroll
            for (int i = 0; i < 4; ++i) {
                int mg = m0 + wr * 64 + i * 16 + lhi * 4;
                int bb = mg >> 10, s = mg & 1023;   // s..s+3, s&3==0
                int bh = bb * NHEAD + hh;
                int sub = t2 * 2 + ((s >> 4) & 1);
                size_t idx = ((size_t)((bh * 32 + (s >> 5)) * 4 + sub)) * 512 +
                             (lr + 32 * ((s >> 3) & 1)) * 8 + (s & 7);
                uint2 pk;
                pk.x = (unsigned)f2b(acc[i][j][0] + bval) |
                       ((unsigned)f2b(acc[i][j][1] + bval) << 16);
                pk.y = (unsigned)f2b(acc[i][j][2] + bval) |
                       ((unsigned)f2b(acc[i][j][3] + bval) << 16);
                *(uint2*)&Vf[idx] = pk;
            }
        }
    }
}

// ---------------------------------------------------------------------------
// Kernel 3: causal flash attention, IN-BLOCK SPLIT-K.
// Block = 4 waves, one (bh, qt). Wave w handles k-tiles kt = w, w+4, ...
// (strided -> balanced), each with private online-softmax state (fragment-
// major coalesced loads, in-register softmax, cvt_pk+permlane, defer-max).
// One barrier; wave 0 merges the 4 partials via LDS (exact split-softmax
// algebra, f32) and writes out. Chains 4x shorter, 4x more waves than r7;
// merge stays on-CU (r6's HBM merge cost 57us).
// grid (B*H=64, 32), block 256. LDS 35.8KB -> 3-4 blocks/CU.
// ---------------------------------------------------------------------------
__global__ __launch_bounds__(256, 3) void attn_kernel(
    const unsigned short* __restrict__ Qf, const unsigned short* __restrict__ Kf,
    const unsigned short* __restrict__ Vf, float* __restrict__ out)
{
    __shared__ alignas(16) float sO[4][2][64][17];  // [wave][d-half][lane][r] +pad
    __shared__ float sM[4][32], sL[4][32];
    int tid = threadIdx.x;
    int lane = tid & 63, w = tid >> 6;
    int l32 = lane & 31, hi = lane >> 5;
    int bh = blockIdx.x;
    int qt = (int)(gridDim.y - 1 - blockIdx.y);  // longest blocks first
    int b = bh >> 3, h = bh & 7;
    int q0 = qt * 32;

    const unsigned short* Qs = Qf + ((size_t)(bh * 32 + qt)) * 2048;
    const unsigned short* Khd = Kf + (size_t)bh * 32 * 2048;
    const unsigned short* Vhd = Vf + (size_t)bh * 32 * 2048;

    bf16x8 qf[4];
#pragma unroll
    for (int d = 0; d < 4; ++d)
        qf[d] = *(const bf16x8*)&Qs[d * 512 + lane * 8];

    f32x16 o0, o1;
#pragma unroll
    for (int r = 0; r < 16; ++r) { o0[r] = 0.f; o1[r] = 0.f; }
    float m = -1e30f, l = 0.f;

    bf16x8 kA[4], vvl[4];

    auto packP = [&](const f32x16& st, bf16x8& pbA, bf16x8& pbB) {
        unsigned u[8];
#pragma unroll
        for (int i = 0; i < 8; ++i) {
            unsigned r_;
            asm("v_cvt_pk_bf16_f32 %0, %1, %2" : "=v"(r_) : "v"(st[2 * i]), "v"(st[2 * i + 1]));
            u[i] = r_;
        }
        asm("v_permlane32_swap_b32 %0, %1" : "+v"(u[0]), "+v"(u[2]));
        asm("v_permlane32_swap_b32 %0, %1" : "+v"(u[1]), "+v"(u[3]));
        asm("v_permlane32_swap_b32 %0, %1" : "+v"(u[4]), "+v"(u[6]));
        asm("v_permlane32_swap_b32 %0, %1" : "+v"(u[5]), "+v"(u[7]));
        uint4 w0 = {u[0], u[1], u[2], u[3]};
        uint4 w1 = {u[4], u[5], u[6], u[7]};
        pbA = __builtin_bit_cast(bf16x8, w0);
        pbB = __builtin_bit_cast(bf16x8, w1);
    };

    for (int kt = w; kt <= qt; kt += 4) {
#pragma unroll
        for (int d = 0; d < 4; ++d)
            kA[d] = *(const bf16x8*)&Khd[(size_t)kt * 2048 + d * 512 + lane * 8];
#pragma unroll
        for (int t2 = 0; t2 < 2; ++t2)
#pragma unroll
            for (int kk = 0; kk < 2; ++kk)
                vvl[t2 * 2 + kk] = *(const bf16x8*)
                    &Vhd[(size_t)kt * 2048 + (t2 * 2 + kk) * 512 + lane * 8];

        f32x16 st0;
#pragma unroll
        for (int r = 0; r < 16; ++r) st0[r] = 0.f;
        __builtin_amdgcn_s_setprio(1);
#pragma unroll
        for (int d = 0; d < 4; ++d) st0 = mfma32(kA[d], qf[d], st0);
        __builtin_amdgcn_s_setprio(0);
        if (kt == qt) {  // diagonal tile: mask k > q
#pragma unroll
            for (int r = 0; r < 16; ++r) {
                int cd = (r & 3) + 8 * (r >> 2) + 4 * hi;
                if (cd > l32) st0[r] = -1e38f;
            }
        }
        float t8[8];
#pragma unroll
        for (int r = 0; r < 8; ++r) t8[r] = fmaxf(st0[r], st0[r + 8]);
        float t4[4];
#pragma unroll
        for (int r = 0; r < 4; ++r) t4[r] = fmaxf(t8[r], t8[r + 4]);
        float tmax = fmaxf(fmaxf(t4[0], t4[2]), fmaxf(t4[1], t4[3]));
        tmax = fmaxf(tmax, __shfl_xor(tmax, 32));
        if (!__all(tmax <= m + 8.0f)) {  // defer-max, exp2 domain
            float mnew = fmaxf(m, tmax);
            float corr = __builtin_amdgcn_exp2f(m - mnew);
#pragma unroll
            for (int r = 0; r < 16; ++r) { o0[r] *= corr; o1[r] *= corr; }
            l *= corr;
            m = mnew;
        }
#pragma unroll
        for (int r = 0; r < 16; ++r) st0[r] = __builtin_amdgcn_exp2f(st0[r] - m);
        float s8[8];
#pragma unroll
        for (int r = 0; r < 8; ++r) s8[r] = st0[r] + st0[r + 8];
        float s4[4];
#pragma unroll
        for (int r = 0; r < 4; ++r) s4[r] = s8[r] + s8[r + 4];
        float ts = (s4[0] + s4[2]) + (s4[1] + s4[3]);
        ts += __shfl_xor(ts, 32);
        l += ts;
        bf16x8 pb0, pb1;
        packP(st0, pb0, pb1);
        __builtin_amdgcn_s_setprio(1);
        o0 = mfma32(vvl[0], pb0, o0); o0 = mfma32(vvl[1], pb1, o0);
        o1 = mfma32(vvl[2], pb0, o1); o1 = mfma32(vvl[3], pb1, o1);
        __builtin_amdgcn_s_setprio(0);
    }

    // publish partials
#pragma unroll
    for (int rr = 0; rr < 4; ++rr) {
        *(float4*)&sO[w][0][lane][rr * 4] =
            make_float4(o0[rr * 4], o0[rr * 4 + 1], o0[rr * 4 + 2], o0[rr * 4 + 3]);
        *(float4*)&sO[w][1][lane][rr * 4] =
            make_float4(o1[rr * 4], o1[rr * 4 + 1], o1[rr * 4 + 2], o1[rr * 4 + 3]);
    }
    if (hi == 0) { sM[w][l32] = m; sL[w][l32] = l; }
    __syncthreads();

    if (w == 0) {
        float m0_ = sM[0][l32], m1_ = sM[1][l32], m2_ = sM[2][l32], m3_ = sM[3][l32];
        float mm = fmaxf(fmaxf(m0_, m1_), fmaxf(m2_, m3_));
        float sc0 = __builtin_amdgcn_exp2f(m0_ - mm);
        float sc1 = __builtin_amdgcn_exp2f(m1_ - mm);
        float sc2 = __builtin_amdgcn_exp2f(m2_ - mm);
        float sc3 = __builtin_amdgcn_exp2f(m3_ - mm);
        float lsum = sL[0][l32] * sc0 + sL[1][l32] * sc1 +
                     sL[2][l32] * sc2 + sL[3][l32] * sc3;
        float inv = 1.0f / lsum;
        float fo0[16], fo1[16];
#pragma unroll
        for (int r = 0; r < 16; ++r) {
            fo0[r] = sO[0][0][lane][r] * sc0 + sO[1][0][lane][r] * sc1 +
                     sO[2][0][lane][r] * sc2 + sO[3][0][lane][r] * sc3;
            fo1[r] = sO[0][1][lane][r] * sc0 + sO[1][1][lane][r] * sc1 +
                     sO[2][1][lane][r] * sc2 + sO[3][1][lane][r] * sc3;
        }
        size_t base = ((size_t)b * EMB + h * HDIM) * SEQ + q0 + l32;
#pragma unroll
        for (int r = 0; r < 16; ++r) {
            int d0 = (r & 3) + 8 * (r >> 2) + 4 * hi;
            out[base + (size_t)d0 * SEQ] = fo0[r] * inv;
            out[base + (size_t)(d0 + 32) * SEQ] = fo1[r] * inv;
        }
    }
}

// ---------------------------------------------------------------------------
extern "C" void kernel_launch(void* const* d_in, const int* in_sizes, int n_in,
                              void* d_out, int out_size, void* d_ws, size_t ws_size,
                              hipStream_t stream) {
    const float* query = (const float*)d_in[0];
    const float* key_  = (const float*)d_in[1];
    const float* Wq    = (const float*)d_in[2];
    const float* bq    = (const float*)d_in[3];
    const float* Wk    = (const float*)d_in[4];
    const float* bk    = (const float*)d_in[5];
    const float* Wv    = (const float*)d_in[6];
    const float* bv    = (const float*)d_in[7];
    float* out = (float*)d_out;

    char* ws = (char*)d_ws;
    unsigned short* Qf = (unsigned short*)(ws);                    // 8 MiB frag-major
    unsigned short* Kf = (unsigned short*)(ws + 8388608);          // 8 MiB frag-major
    unsigned short* Vf = (unsigned short*)(ws + 16777216);         // 8 MiB frag-major
    unsigned short* Xq = (unsigned short*)(ws + 25165824);         // 4 MiB (B,S,C) swz
    unsigned short* Xk = (unsigned short*)(ws + 29360128);         // 4 MiB (B,S,C) swz
    // Wc (1536x256 bf16 swizzled, 768 KiB) in the tail of d_out; attn
    // overwrites all of d_out afterwards (stream-ordered) -> free scratch.
    unsigned short* Wc = (unsigned short*)((char*)d_out + 16777216 - 1048576);

    prep_kernel<<<dim3(16, 4, 19), 256, 0, stream>>>(query, key_, Wq, Wk, Wv, Xq, Xk, Wc);
    proj_kernel<<<dim3(12, 64), 256, 0, stream>>>(Xq, Xk, Wc, bq, bk, bv, Qf, Kf, Vf);
    attn_kernel<<<dim3(BATCH * NHEAD, SEQ / 32), 256, 0, stream>>>(Qf, Kf, Vf, out);
}